// Round 15
// baseline (284.948 us; speedup 1.0000x reference)
//
#include <hip/hip_runtime.h>
#include <hip/hip_bf16.h>
#include <hip/hip_fp16.h>

// Problem constants (match reference)
#define TT 64
#define GN 1024
#define DK 128
#define NN (TT * GN)      // 65536
#define OUTC 131          // 3 + 128
#define TAU 5e-3f         // rescue threshold, 8.8 sigma of fp16-induced sim error
#define CHUNK 64          // rescue rows staged per LDS chunk

typedef _Float16 f16x8 __attribute__((ext_vector_type(8)));
typedef float    f32x4 __attribute__((ext_vector_type(4)));

// fp32 -> fp16 round-to-nearest-even, as raw 16 bits
__device__ __forceinline__ unsigned f2h(float f) {
    return (unsigned)__half_as_ushort(__float2half(f));
}

// async global->LDS, 16 B per lane; LDS dest must be lane-contiguous (m104)
__device__ __forceinline__ void gload_lds16(const void* g, void* l) {
    __builtin_amdgcn_global_load_lds(
        (const __attribute__((address_space(1))) unsigned int*)g,
        (__attribute__((address_space(3))) unsigned int*)l, 16, 0, 0);
}

// ---------------------------------------------------------------------------
// Kernel 1: fused fp16 conversion + per-row reciprocal norms (fp64 accum).
// Also zeroes rcnt (block 0) and clen (first 256 blocks) - no memset dispatches.
// ---------------------------------------------------------------------------
__global__ void kconv(const float* __restrict__ feat, unsigned* __restrict__ fh,
                      float* __restrict__ rnf, double* __restrict__ rnd,
                      int* __restrict__ rcnt, int* __restrict__ clen) {
    if (blockIdx.x == 0 && threadIdx.x < 63) rcnt[threadIdx.x] = 0;
    if (blockIdx.x < 256) clen[blockIdx.x * 256 + threadIdx.x] = 0;
    int row  = blockIdx.x * 4 + (threadIdx.x >> 6);
    int lane = threadIdx.x & 63;
    const float* fr = feat + (size_t)row * DK;
    float2 v = *(const float2*)(fr + lane * 2);
    fh[(size_t)row * 64 + lane] = f2h(v.x) | (f2h(v.y) << 16);
    double s = (double)v.x * (double)v.x + (double)v.y * (double)v.y;
    #pragma unroll
    for (int off = 32; off > 0; off >>= 1)
        s += __shfl_down(s, off);
    if (lane == 0) {
        double m = sqrt(s);
        if (m < 1e-6) m = 1e-6;
        double r = 1.0 / m;
        rnd[row] = r;
        rnf[row] = (float)r;
    }
}

// ---------------------------------------------------------------------------
// Kernel 2: 4032 independent 128x128x128 GEMM tile blocks (t, mt, nt).
// Operand-SWAPPED MFMA: D[m=B-col][n=A-row] so lane la indexes the sim ROW.
// (unchanged from R12-R14 - verified absmax 0)
// ---------------------------------------------------------------------------
__global__ __launch_bounds__(256) void ksim(const unsigned* __restrict__ fh,
                                            const float* __restrict__ rnf,
                                            float4* __restrict__ tws) {
    __shared__ int Atile[8192];    // 128 rows x 16 granules (32 KB)
    __shared__ int Btile[8192];

    int id = blockIdx.x;           // t*64 + mt*8 + nt
    int t  = id >> 6;              // 0..62
    int mt = (id >> 3) & 7;
    int nt = id & 7;

    int tid  = threadIdx.x;
    int wave = tid >> 6;
    int lane = tid & 63;
    int la = lane & 15;
    int lq = lane >> 4;
    int wr = (wave & 1) * 64;      // wave row offset
    int wc = (wave >> 1) * 64;     // wave col offset

    const int* Ag = (const int*)fh + ((size_t)t * GN + mt * 128) * 64;
    const int* Bg = (const int*)fh + ((size_t)(t + 1) * GN + nt * 128) * 64;

    #pragma unroll
    for (int i = 0; i < 8; ++i) {
        int L = i * 256 + tid;         // granule index in tile
        int row = L >> 4, colL = L & 15;
        int colG = colL ^ (row & 7);
        gload_lds16(Ag + row * 64 + colG * 4, &Atile[L * 4]);
        gload_lds16(Bg + row * 64 + colG * 4, &Btile[L * 4]);
    }
    __syncthreads();                   // includes vmcnt(0) drain

    f32x4 acc[4][4];
    #pragma unroll
    for (int at = 0; at < 4; ++at)
        #pragma unroll
        for (int ct = 0; ct < 4; ++ct) acc[at][ct] = (f32x4){0.f, 0.f, 0.f, 0.f};

    #pragma unroll
    for (int kc = 0; kc < 4; ++kc) {
        int sw = ((kc * 4 + lq) ^ (la & 7)) << 2;   // swizzled in-row int offset
        f16x8 af[4], bf[4];
        #pragma unroll
        for (int x = 0; x < 4; ++x) {
            af[x] = __builtin_bit_cast(f16x8, *(const int4*)&Atile[(wr + x * 16 + la) * 64 + sw]);
            bf[x] = __builtin_bit_cast(f16x8, *(const int4*)&Btile[(wc + x * 16 + la) * 64 + sw]);
        }
        #pragma unroll
        for (int at = 0; at < 4; ++at)
            #pragma unroll
            for (int ct = 0; ct < 4; ++ct)
                acc[at][ct] = __builtin_amdgcn_mfma_f32_16x16x32_f16(
                    bf[ct], af[at], acc[at][ct], 0, 0, 0);   // SWAPPED
    }

    // per-lane top-2: slot s=at -> row wr+at*16+la; cols wc+ct*16+lq*4+reg
    float t1[4], t2[4]; int i1[4];
    #pragma unroll
    for (int s = 0; s < 4; ++s) { t1[s] = -3.4e38f; t2[s] = -3.4e38f; i1[s] = 0x7fffffff; }

    const float* rB = rnf + (size_t)(t + 1) * GN + nt * 128;
    #pragma unroll
    for (int ct = 0; ct < 4; ++ct) {               // ct asc, reg asc -> n asc
        float4 rnv = *(const float4*)&rB[wc + ct * 16 + lq * 4];
        int nbase = nt * 128 + wc + ct * 16 + lq * 4;
        float rn[4] = {rnv.x, rnv.y, rnv.z, rnv.w};
        #pragma unroll
        for (int at = 0; at < 4; ++at) {
            #pragma unroll
            for (int reg = 0; reg < 4; ++reg) {
                float v = acc[at][ct][reg] * rn[reg];
                t2[at] = fmaxf(t2[at], fminf(v, t1[at]));   // med3(v,t1,t2)
                if (v > t1[at]) { t1[at] = v; i1[at] = nbase + reg; }
            }
        }
    }

    // butterfly top-2 merge over the 4 lq quads (same la = same row)
    #pragma unroll
    for (int m = 16; m <= 32; m <<= 1) {
        #pragma unroll
        for (int s = 0; s < 4; ++s) {
            float o1 = __shfl_xor(t1[s], m);
            float o2 = __shfl_xor(t2[s], m);
            int   oi = __shfl_xor(i1[s], m);
            bool take = (o1 > t1[s]) || (o1 == t1[s] && oi < i1[s]);
            float nt2 = take ? fmaxf(o2, t1[s]) : fmaxf(t2[s], o1);
            if (take) { t1[s] = o1; i1[s] = oi; }
            t2[s] = nt2;
        }
    }

    // cross-wave merge (2 column halves) via overlay on Atile
    __syncthreads();                   // all tile reads done
    float* mv1 = (float*)Atile;        // [128][2]
    float* mv2 = mv1 + 256;
    int*   mi1 = (int*)(mv2 + 256);
    if (lq == 0) {                     // lanes 0..15 hold merged rows
        #pragma unroll
        for (int s = 0; s < 4; ++s) {
            int row = wr + s * 16 + la;
            int idx = row * 2 + (wave >> 1);
            mv1[idx] = t1[s]; mv2[idx] = t2[s]; mi1[idx] = i1[s];
        }
    }
    __syncthreads();

    if (tid < 128) {
        float best = mv1[tid * 2], sec, bw2 = mv2[tid * 2];
        int bi = mi1[tid * 2];
        float v1 = mv1[tid * 2 + 1], v2 = mv2[tid * 2 + 1];
        int  ii = mi1[tid * 2 + 1];
        if (v1 > best || (v1 == best && ii < bi)) {
            sec = fmaxf(best, v2); best = v1; bi = ii;   // winner half 1
        } else {
            sec = fmaxf(v1, bw2);
        }
        float4 o; o.x = best; o.y = sec; o.z = __int_as_float(bi); o.w = 0.f;
        // [nt][t][grow] layout: full-line 2 KB writes per block
        tws[((size_t)(nt * 63 + t)) * GN + mt * 128 + tid] = o;
    }
}

// ---------------------------------------------------------------------------
// Kernel 3: merge 8 colblock candidates per row; gap<TAU -> per-t rescue list.
// ---------------------------------------------------------------------------
__global__ void kmerge(const float4* __restrict__ tws, unsigned short* __restrict__ nxt16,
                       int* __restrict__ rcnt, int* __restrict__ rlistT) {
    int idx = blockIdx.x * 256 + threadIdx.x;      // 0..64511
    int t = idx >> 10, grow = idx & 1023;
    float best = -3.4e38f, sec = -3.4e38f, bw2 = -3.4e38f;
    int bi = 0x7fffffff;
    #pragma unroll
    for (int nb = 0; nb < 8; ++nb) {               // nb ascending = n ascending
        float4 v = tws[((size_t)(nb * 63 + t)) * GN + grow];
        int ii = __float_as_int(v.z);
        if (v.x > best || (v.x == best && ii < bi)) {
            sec = fmaxf(sec, best);
            best = v.x; bi = ii; bw2 = v.y;
        } else {
            sec = fmaxf(sec, v.x);
        }
    }
    sec = fmaxf(sec, bw2);
    if (best - sec < TAU) {
        int p = atomicAdd(&rcnt[t], 1);
        rlistT[t * 1024 + p] = grow;
    } else {
        nxt16[idx] = (unsigned short)bi;
    }
}

// fp64 4-FMA accumulate of one float4 pair (same order as R13/R14 chains)
#define ACC4(sv, aa, bb)                                   \
    sv = fma((double)(aa).x, (double)(bb).x, sv);          \
    sv = fma((double)(aa).y, (double)(bb).y, sv);          \
    sv = fma((double)(aa).z, (double)(bb).z, sv);          \
    sv = fma((double)(aa).w, (double)(bb).w, sv);

// ---------------------------------------------------------------------------
// Kernel 4: fp64 rescue v4. Block = (t, quarter q): 256 B-rows; each thread
// owns TWO rows (h, h+128) x one k-half -> the per-thread A-reads are shared
// by both rows (halved LDS traffic). 252 blocks -> 1 block/CU. Rescues are
// processed in batches of 4 with the 4 waves reducing 4 rescues in parallel
// (2 barriers per 4 rescues). No global ops between barriers. Exact fp64
// per-row summation order matches R14 (absmax 0).
// ---------------------------------------------------------------------------
__global__ __launch_bounds__(256) void krescue(const float* __restrict__ feat,
                                               const double* __restrict__ rnd,
                                               const int* __restrict__ rcnt,
                                               const int* __restrict__ rlistT,
                                               double* __restrict__ pbv,
                                               int* __restrict__ pbi) {
    __shared__ float  arows[CHUNK][128];   // 32 KB
    __shared__ int    rl[CHUNK];
    __shared__ double cv[4][128];          // 4 KB
    __shared__ int    ci[4][128];          // 2 KB
    __shared__ double resv[CHUNK];
    __shared__ int    resi[CHUNK];
    int bid = blockIdx.x;               // t*4 + q
    int t = bid >> 2, q = bid & 3;
    int nr = rcnt[t];
    if (nr == 0) return;
    int tid  = threadIdx.x;
    int wave = tid >> 6, lane = tid & 63;
    int row  = tid >> 1;                // 0..127
    int par  = tid & 1;                 // k-half: 0 -> [0,64), 1 -> [64,128)
    int h0 = q * 256 + row;             // first owned B row
    int h1 = h0 + 128;                  // second owned B row

    const float* B0 = feat + ((size_t)(t + 1) * GN + h0) * DK + par * 64;
    const float* B1 = feat + ((size_t)(t + 1) * GN + h1) * DK + par * 64;
    float4 br0[16], br1[16];
    #pragma unroll
    for (int i = 0; i < 16; ++i) {
        br0[i] = *(const float4*)(B0 + i * 4);
        br1[i] = *(const float4*)(B1 + i * 4);
    }
    double rb0 = rnd[(t + 1) * GN + h0];
    double rb1 = rnd[(t + 1) * GN + h1];

    for (int c0 = 0; c0 < nr; c0 += CHUNK) {
        int cn = min(CHUNK, nr - c0);
        if (tid < cn) rl[tid] = rlistT[t * 1024 + c0 + tid];
        __syncthreads();
        for (int e = tid; e < cn * 32; e += 256) {
            int r = e >> 5, k = e & 31;
            *(float4*)&arows[r][k * 4] =
                *(const float4*)(feat + ((size_t)t * GN + rl[r]) * DK + k * 4);
        }
        __syncthreads();

        for (int rb = 0; rb < cn; rb += 4) {
            int rn4 = min(4, cn - rb);
            for (int rr = 0; rr < rn4; ++rr) {     // no barriers inside
                const float* ap = &arows[rb + rr][par * 64];
                double s0=0.0,s1=0.0,s2=0.0,s3=0.0;
                double u0=0.0,u1=0.0,u2=0.0,u3=0.0;
                #pragma unroll
                for (int i = 0; i < 16; i += 4) {
                    float4 a0 = *(const float4*)(ap + i * 4);
                    float4 a1 = *(const float4*)(ap + i * 4 + 4);
                    float4 a2 = *(const float4*)(ap + i * 4 + 8);
                    float4 a3 = *(const float4*)(ap + i * 4 + 12);
                    ACC4(s0, a0, br0[i])     ACC4(s1, a1, br0[i + 1])
                    ACC4(s2, a2, br0[i + 2]) ACC4(s3, a3, br0[i + 3])
                    ACC4(u0, a0, br1[i])     ACC4(u1, a1, br1[i + 1])
                    ACC4(u2, a2, br1[i + 2]) ACC4(u3, a3, br1[i + 3])
                }
                double s = (s0 + s1) + (s2 + s3);
                double u = (u0 + u1) + (u2 + u3);
                double so = __shfl_xor(s, 1);      // partner k-half
                double uo = __shfl_xor(u, 1);
                if (par == 0) {
                    double v0 = (s + so) * rb0;
                    double v1 = (u + uo) * rb1;
                    if (v1 > v0) { cv[rr][row] = v1; ci[rr][row] = h1; }
                    else         { cv[rr][row] = v0; ci[rr][row] = h0; }  // tie -> h0
                }
            }
            __syncthreads();
            if (wave < rn4) {                      // 4 parallel reductions
                double v1 = cv[wave][lane];      int i1 = ci[wave][lane];
                double v2 = cv[wave][lane + 64]; int i2 = ci[wave][lane + 64];
                if (v2 > v1 || (v2 == v1 && i2 < i1)) { v1 = v2; i1 = i2; }
                #pragma unroll
                for (int off = 32; off > 0; off >>= 1) {
                    double ov = __shfl_down(v1, off);
                    int    oi = __shfl_down(i1, off);
                    if (ov > v1 || (ov == v1 && oi < i1)) { v1 = ov; i1 = oi; }
                }
                if (lane == 0) { resv[rb + wave] = v1; resi[rb + wave] = i1; }
            }
            __syncthreads();
        }

        if (tid < cn) {                            // bulk flush per chunk
            pbv[(size_t)bid * 1024 + c0 + tid] = resv[tid];
            pbi[(size_t)bid * 1024 + c0 + tid] = resi[tid];
        }
        __syncthreads();
    }
}

// ---------------------------------------------------------------------------
// Kernel 5: rescue-finalize + chain propagation + (folded) chain lengths.
// Pure LDS in the barrier loop (R9-proven); the length histogram runs AFTER
// the loop as fire-and-forget atomics (chain id == start node index, fits
// ushort: max 63*1024+1023 = 65535).
// ---------------------------------------------------------------------------
__global__ __launch_bounds__(1024) void kgraph(const unsigned short* __restrict__ nxt16,
                                               const int* __restrict__ rcnt,
                                               const int* __restrict__ rlistT,
                                               const double* __restrict__ pbv,
                                               const int* __restrict__ pbi,
                                               int* __restrict__ chain_of,
                                               int* __restrict__ clen) {
    __shared__ unsigned short ns[64 * 1024];   // 128 KB (row 63 unused pad)
    __shared__ int winner[2 * GN];             // 8 KB double-buffer
    __shared__ int rc[64];
    int g = threadIdx.x;                       // 0..1023

    #pragma unroll
    for (int i = 0; i < 8; ++i)
        gload_lds16((const char*)nxt16 + ((size_t)i * 1024 + g) * 16,
                    (char*)ns + ((size_t)i * 1024 + g) * 16);

    if (g < 63) rc[g] = rcnt[g];
    winner[g] = 0x7fffffff;
    chain_of[g] = g;                           // group 0: identity
    __syncthreads();                           // drains the global_load_lds

    // rescue fix-ups: thread g -> t = g>>4, ri = (g&15)+16k  (~2 iters/thread)
    int t0 = g >> 4;
    if (t0 < TT - 1) {
        for (int ri = g & 15; ri < rc[t0]; ri += 16) {
            double bv = -1e300; int bi = 0x7fffffff;
            #pragma unroll
            for (int q = 0; q < 4; ++q) {
                double v  = pbv[(size_t)(t0 * 4 + q) * 1024 + ri];
                int    ii = pbi[(size_t)(t0 * 4 + q) * 1024 + ri];
                if (v > bv || (v == bv && ii < bi)) { bv = v; bi = ii; }
            }
            ns[t0 * GN + rlistT[t0 * 1024 + ri]] = (unsigned short)bi;
        }
    }
    __syncthreads();

    int mychain = g;
    for (int t = 0; t < TT - 1; ++t) {
        int* Wa = winner + (t & 1) * GN;
        int* Wb = winner + ((t + 1) & 1) * GN;
        int j = ns[t * GN + g];                // local index in group t+1
        atomicMin(&Wa[j], mychain);
        Wb[g] = 0x7fffffff;
        __syncthreads();
        int w = Wa[g];
        mychain = (w == 0x7fffffff) ? (((t + 1) << 10) | g) : w;
        ns[t * GN + g] = (unsigned short)mychain;   // recycle consumed slot
        __syncthreads();
    }

    // flush chain_of + length histogram (fire-and-forget, outside the loop)
    atomicAdd(&clen[g], 1);                    // group-0 node g -> chain g
    for (int t = 0; t < TT - 1; ++t) {
        int c = ns[t * GN + g];
        chain_of[(t + 1) * GN + g] = c;
        atomicAdd(&clen[c], 1);
    }
}

// ---------------------------------------------------------------------------
// Kernel 6: per-block (1024-elem, coalesced) exclusive scan of kept lengths.
// ---------------------------------------------------------------------------
__global__ __launch_bounds__(1024) void kseg(const int* __restrict__ chain_of,
                                             const int* __restrict__ clen,
                                             const int* __restrict__ minp,
                                             int* __restrict__ oloc,
                                             int* __restrict__ partial) {
    __shared__ int ps[1024];
    int b = blockIdx.x, tid = threadIdx.x;
    int i = b * 1024 + tid;
    int ml = *minp;
    int cl = clen[i];
    int v = (chain_of[i] == i && cl >= ml) ? cl : 0;
    ps[tid] = v;
    __syncthreads();
    for (int off = 1; off < 1024; off <<= 1) {
        int add = (tid >= off) ? ps[tid - off] : 0;
        __syncthreads();
        ps[tid] += add;
        __syncthreads();
    }
    oloc[i] = ps[tid] - v;              // exclusive within block
    if (tid == 1023) partial[b] = ps[tid];
}

// ---------------------------------------------------------------------------
// Kernel 7: fused partial-scan + scatter + tail-zero.
// ---------------------------------------------------------------------------
__global__ __launch_bounds__(256) void kout(const float* __restrict__ coor,
                                            const float* __restrict__ feat,
                                            const int* __restrict__ chain_of,
                                            const int* __restrict__ clen,
                                            const int* __restrict__ oloc,
                                            const int* __restrict__ partial,
                                            const int* __restrict__ minp,
                                            float* __restrict__ out) {
    __shared__ int pb[64];
    __shared__ int stot;
    int tid = threadIdx.x;
    if (tid < 64) {
        int v = partial[tid];
        int acc = v;
        #pragma unroll
        for (int off = 1; off < 64; off <<= 1) {
            int o = __shfl_up(acc, off);
            if (tid >= off) acc += o;
        }
        pb[tid] = acc - v;
        if (tid == 63) stot = acc;
    }
    __syncthreads();

    int node = blockIdx.x * 4 + (tid >> 6);
    int lane = tid & 63;
    int s = chain_of[node];
    if (clen[s] >= *minp) {
        int row = oloc[s] + pb[s >> 10] + (node >> 10) - (s >> 10);
        float* orow = out + (size_t)row * OUTC;
        const float* f = feat + (size_t)node * DK;
        if (lane < 3) orow[lane] = coor[(size_t)node * 3 + lane];
        orow[3 + lane]  = f[lane];
        orow[67 + lane] = f[64 + lane];
    }

    int zrow = stot + blockIdx.x * 4 + (tid >> 6);
    if (zrow < NN) {
        float* orow = out + (size_t)zrow * OUTC;
        orow[lane] = 0.f;
        orow[64 + lane] = 0.f;
        if (lane < 3) orow[128 + lane] = 0.f;
    }
}

// ---------------------------------------------------------------------------
extern "C" void kernel_launch(void* const* d_in, const int* in_sizes, int n_in,
                              void* d_out, int out_size, void* d_ws, size_t ws_size,
                              hipStream_t stream) {
    const float* coor   = (const float*)d_in[0];   // [N,3]
    const float* feat   = (const float*)d_in[1];   // [N,128]
    const int*   minlen = (const int*)d_in[2];     // scalar
    float*       out    = (float*)d_out;           // [N,131] fp32

    char* ws = (char*)d_ws;
    double*         rnd      = (double*)(ws);                  // 512 KB
    float*          rnf      = (float*)(ws + 524288);          // 256 KB
    unsigned short* nxt16    = (unsigned short*)(ws + 786432); // 128 KB
    int*            chain_of = (int*)(ws + 917504);            // 256 KB
    int*            clen     = (int*)(ws + 1179648);           // 256 KB
    int*            oloc     = (int*)(ws + 1441792);           // 256 KB
    int*            rcnt     = (int*)(ws + 1703936);           // 63 ints
    int*            partial  = (int*)(ws + 1704192);           // 256 B
    int*            rlistT   = (int*)(ws + 1705216);           // 252 KB
    unsigned*       fh       = (unsigned*)(ws + 2097152);      // 16 MB
    float4*         tws      = (float4*)(ws + 18874368);       // 8.25 MB
    // pbv/pbi overlay tws (tws dead after kmerge; krescue runs after kmerge)
    double*         pbv      = (double*)(ws + 18874368);       // 252*1024*8 ~ 2 MB
    int*            pbi      = (int*)(ws + 18874368 + 2064384);// ~1 MB

    kconv<<<NN / 4, 256, 0, stream>>>(feat, fh, rnf, rnd, rcnt, clen);

    ksim<<<63 * 64, 256, 0, stream>>>(fh, rnf, tws);

    kmerge<<<63 * GN / 256, 256, 0, stream>>>(tws, nxt16, rcnt, rlistT);
    krescue<<<63 * 4, 256, 0, stream>>>(feat, rnd, rcnt, rlistT, pbv, pbi);

    kgraph<<<1, GN, 0, stream>>>(nxt16, rcnt, rlistT, pbv, pbi, chain_of, clen);
    kseg<<<64, 1024, 0, stream>>>(chain_of, clen, minlen, oloc, partial);
    kout<<<NN / 4, 256, 0, stream>>>(coor, feat, chain_of, clen, oloc, partial,
                                     minlen, out);
}

// Round 16
// 231.556 us; speedup vs baseline: 1.2306x; 1.2306x over previous
//
#include <hip/hip_runtime.h>
#include <hip/hip_bf16.h>
#include <hip/hip_fp16.h>

// Problem constants (match reference)
#define TT 64
#define GN 1024
#define DK 128
#define NN (TT * GN)      // 65536
#define OUTC 131          // 3 + 128
#define TAU 5e-3f         // rescue threshold, 8.8 sigma of fp16-induced sim error
#define CHUNK 64          // rescue rows staged per LDS chunk

typedef _Float16 f16x8 __attribute__((ext_vector_type(8)));
typedef float    f32x4 __attribute__((ext_vector_type(4)));

// fp32 -> fp16 round-to-nearest-even, as raw 16 bits
__device__ __forceinline__ unsigned f2h(float f) {
    return (unsigned)__half_as_ushort(__float2half(f));
}

// async global->LDS, 16 B per lane; LDS dest must be lane-contiguous (m104)
__device__ __forceinline__ void gload_lds16(const void* g, void* l) {
    __builtin_amdgcn_global_load_lds(
        (const __attribute__((address_space(1))) unsigned int*)g,
        (__attribute__((address_space(3))) unsigned int*)l, 16, 0, 0);
}

// ---------------------------------------------------------------------------
// Kernel 1: fused fp16 conversion + per-row reciprocal norms (fp64 accum).
// Also zeroes rcnt (block 0) and clen (first 256 blocks) - no memset dispatches.
// ---------------------------------------------------------------------------
__global__ void kconv(const float* __restrict__ feat, unsigned* __restrict__ fh,
                      float* __restrict__ rnf, double* __restrict__ rnd,
                      int* __restrict__ rcnt, int* __restrict__ clen) {
    if (blockIdx.x == 0 && threadIdx.x < 63) rcnt[threadIdx.x] = 0;
    if (blockIdx.x < 256) clen[blockIdx.x * 256 + threadIdx.x] = 0;
    int row  = blockIdx.x * 4 + (threadIdx.x >> 6);
    int lane = threadIdx.x & 63;
    const float* fr = feat + (size_t)row * DK;
    float2 v = *(const float2*)(fr + lane * 2);
    fh[(size_t)row * 64 + lane] = f2h(v.x) | (f2h(v.y) << 16);
    double s = (double)v.x * (double)v.x + (double)v.y * (double)v.y;
    #pragma unroll
    for (int off = 32; off > 0; off >>= 1)
        s += __shfl_down(s, off);
    if (lane == 0) {
        double m = sqrt(s);
        if (m < 1e-6) m = 1e-6;
        double r = 1.0 / m;
        rnd[row] = r;
        rnf[row] = (float)r;
    }
}

// ---------------------------------------------------------------------------
// Kernel 2: 4032 independent 128x128x128 GEMM tile blocks (t, mt, nt).
// Operand-SWAPPED MFMA: D[m=B-col][n=A-row] so lane la indexes the sim ROW.
// (unchanged from R12-R15 - verified absmax 0)
// ---------------------------------------------------------------------------
__global__ __launch_bounds__(256) void ksim(const unsigned* __restrict__ fh,
                                            const float* __restrict__ rnf,
                                            float4* __restrict__ tws) {
    __shared__ int Atile[8192];    // 128 rows x 16 granules (32 KB)
    __shared__ int Btile[8192];

    int id = blockIdx.x;           // t*64 + mt*8 + nt
    int t  = id >> 6;              // 0..62
    int mt = (id >> 3) & 7;
    int nt = id & 7;

    int tid  = threadIdx.x;
    int wave = tid >> 6;
    int lane = tid & 63;
    int la = lane & 15;
    int lq = lane >> 4;
    int wr = (wave & 1) * 64;      // wave row offset
    int wc = (wave >> 1) * 64;     // wave col offset

    const int* Ag = (const int*)fh + ((size_t)t * GN + mt * 128) * 64;
    const int* Bg = (const int*)fh + ((size_t)(t + 1) * GN + nt * 128) * 64;

    #pragma unroll
    for (int i = 0; i < 8; ++i) {
        int L = i * 256 + tid;         // granule index in tile
        int row = L >> 4, colL = L & 15;
        int colG = colL ^ (row & 7);
        gload_lds16(Ag + row * 64 + colG * 4, &Atile[L * 4]);
        gload_lds16(Bg + row * 64 + colG * 4, &Btile[L * 4]);
    }
    __syncthreads();                   // includes vmcnt(0) drain

    f32x4 acc[4][4];
    #pragma unroll
    for (int at = 0; at < 4; ++at)
        #pragma unroll
        for (int ct = 0; ct < 4; ++ct) acc[at][ct] = (f32x4){0.f, 0.f, 0.f, 0.f};

    #pragma unroll
    for (int kc = 0; kc < 4; ++kc) {
        int sw = ((kc * 4 + lq) ^ (la & 7)) << 2;   // swizzled in-row int offset
        f16x8 af[4], bf[4];
        #pragma unroll
        for (int x = 0; x < 4; ++x) {
            af[x] = __builtin_bit_cast(f16x8, *(const int4*)&Atile[(wr + x * 16 + la) * 64 + sw]);
            bf[x] = __builtin_bit_cast(f16x8, *(const int4*)&Btile[(wc + x * 16 + la) * 64 + sw]);
        }
        #pragma unroll
        for (int at = 0; at < 4; ++at)
            #pragma unroll
            for (int ct = 0; ct < 4; ++ct)
                acc[at][ct] = __builtin_amdgcn_mfma_f32_16x16x32_f16(
                    bf[ct], af[at], acc[at][ct], 0, 0, 0);   // SWAPPED
    }

    // per-lane top-2: slot s=at -> row wr+at*16+la; cols wc+ct*16+lq*4+reg
    float t1[4], t2[4]; int i1[4];
    #pragma unroll
    for (int s = 0; s < 4; ++s) { t1[s] = -3.4e38f; t2[s] = -3.4e38f; i1[s] = 0x7fffffff; }

    const float* rB = rnf + (size_t)(t + 1) * GN + nt * 128;
    #pragma unroll
    for (int ct = 0; ct < 4; ++ct) {               // ct asc, reg asc -> n asc
        float4 rnv = *(const float4*)&rB[wc + ct * 16 + lq * 4];
        int nbase = nt * 128 + wc + ct * 16 + lq * 4;
        float rn[4] = {rnv.x, rnv.y, rnv.z, rnv.w};
        #pragma unroll
        for (int at = 0; at < 4; ++at) {
            #pragma unroll
            for (int reg = 0; reg < 4; ++reg) {
                float v = acc[at][ct][reg] * rn[reg];
                t2[at] = fmaxf(t2[at], fminf(v, t1[at]));   // med3(v,t1,t2)
                if (v > t1[at]) { t1[at] = v; i1[at] = nbase + reg; }
            }
        }
    }

    // butterfly top-2 merge over the 4 lq quads (same la = same row)
    #pragma unroll
    for (int m = 16; m <= 32; m <<= 1) {
        #pragma unroll
        for (int s = 0; s < 4; ++s) {
            float o1 = __shfl_xor(t1[s], m);
            float o2 = __shfl_xor(t2[s], m);
            int   oi = __shfl_xor(i1[s], m);
            bool take = (o1 > t1[s]) || (o1 == t1[s] && oi < i1[s]);
            float nt2 = take ? fmaxf(o2, t1[s]) : fmaxf(t2[s], o1);
            if (take) { t1[s] = o1; i1[s] = oi; }
            t2[s] = nt2;
        }
    }

    // cross-wave merge (2 column halves) via overlay on Atile
    __syncthreads();                   // all tile reads done
    float* mv1 = (float*)Atile;        // [128][2]
    float* mv2 = mv1 + 256;
    int*   mi1 = (int*)(mv2 + 256);
    if (lq == 0) {                     // lanes 0..15 hold merged rows
        #pragma unroll
        for (int s = 0; s < 4; ++s) {
            int row = wr + s * 16 + la;
            int idx = row * 2 + (wave >> 1);
            mv1[idx] = t1[s]; mv2[idx] = t2[s]; mi1[idx] = i1[s];
        }
    }
    __syncthreads();

    if (tid < 128) {
        float best = mv1[tid * 2], sec, bw2 = mv2[tid * 2];
        int bi = mi1[tid * 2];
        float v1 = mv1[tid * 2 + 1], v2 = mv2[tid * 2 + 1];
        int  ii = mi1[tid * 2 + 1];
        if (v1 > best || (v1 == best && ii < bi)) {
            sec = fmaxf(best, v2); best = v1; bi = ii;   // winner half 1
        } else {
            sec = fmaxf(v1, bw2);
        }
        float4 o; o.x = best; o.y = sec; o.z = __int_as_float(bi); o.w = 0.f;
        // [nt][t][grow] layout: full-line 2 KB writes per block
        tws[((size_t)(nt * 63 + t)) * GN + mt * 128 + tid] = o;
    }
}

// ---------------------------------------------------------------------------
// Kernel 3: merge 8 colblock candidates per row; gap<TAU -> per-t rescue list.
// ---------------------------------------------------------------------------
__global__ void kmerge(const float4* __restrict__ tws, unsigned short* __restrict__ nxt16,
                       int* __restrict__ rcnt, int* __restrict__ rlistT) {
    int idx = blockIdx.x * 256 + threadIdx.x;      // 0..64511
    int t = idx >> 10, grow = idx & 1023;
    float best = -3.4e38f, sec = -3.4e38f, bw2 = -3.4e38f;
    int bi = 0x7fffffff;
    #pragma unroll
    for (int nb = 0; nb < 8; ++nb) {               // nb ascending = n ascending
        float4 v = tws[((size_t)(nb * 63 + t)) * GN + grow];
        int ii = __float_as_int(v.z);
        if (v.x > best || (v.x == best && ii < bi)) {
            sec = fmaxf(sec, best);
            best = v.x; bi = ii; bw2 = v.y;
        } else {
            sec = fmaxf(sec, v.x);
        }
    }
    sec = fmaxf(sec, bw2);
    if (best - sec < TAU) {
        int p = atomicAdd(&rcnt[t], 1);
        rlistT[t * 1024 + p] = grow;
    } else {
        nxt16[idx] = (unsigned short)bi;
    }
}

// fp64 4-FMA accumulate of one float4 pair (same order as R13-R15 chains)
#define ACC4(sv, aa, bb)                                   \
    sv = fma((double)(aa).x, (double)(bb).x, sv);          \
    sv = fma((double)(aa).y, (double)(bb).y, sv);          \
    sv = fma((double)(aa).z, (double)(bb).z, sv);          \
    sv = fma((double)(aa).w, (double)(bb).w, sv);

// ---------------------------------------------------------------------------
// Kernel 4: fp64 rescue v4 (R15-proven). Block = (t, quarter q): 256 B-rows;
// each thread owns TWO rows (h, h+128) x one k-half -> per-thread A-reads
// shared by both rows. 252 blocks -> 1 block/CU. Batch-4 rescues, 4 waves
// reduce in parallel. No global ops between barriers.
// ---------------------------------------------------------------------------
__global__ __launch_bounds__(256) void krescue(const float* __restrict__ feat,
                                               const double* __restrict__ rnd,
                                               const int* __restrict__ rcnt,
                                               const int* __restrict__ rlistT,
                                               double* __restrict__ pbv,
                                               int* __restrict__ pbi) {
    __shared__ float  arows[CHUNK][128];   // 32 KB
    __shared__ int    rl[CHUNK];
    __shared__ double cv[4][128];          // 4 KB
    __shared__ int    ci[4][128];          // 2 KB
    __shared__ double resv[CHUNK];
    __shared__ int    resi[CHUNK];
    int bid = blockIdx.x;               // t*4 + q
    int t = bid >> 2, q = bid & 3;
    int nr = rcnt[t];
    if (nr == 0) return;
    int tid  = threadIdx.x;
    int wave = tid >> 6, lane = tid & 63;
    int row  = tid >> 1;                // 0..127
    int par  = tid & 1;                 // k-half: 0 -> [0,64), 1 -> [64,128)
    int h0 = q * 256 + row;             // first owned B row
    int h1 = h0 + 128;                  // second owned B row

    const float* B0 = feat + ((size_t)(t + 1) * GN + h0) * DK + par * 64;
    const float* B1 = feat + ((size_t)(t + 1) * GN + h1) * DK + par * 64;
    float4 br0[16], br1[16];
    #pragma unroll
    for (int i = 0; i < 16; ++i) {
        br0[i] = *(const float4*)(B0 + i * 4);
        br1[i] = *(const float4*)(B1 + i * 4);
    }
    double rb0 = rnd[(t + 1) * GN + h0];
    double rb1 = rnd[(t + 1) * GN + h1];

    for (int c0 = 0; c0 < nr; c0 += CHUNK) {
        int cn = min(CHUNK, nr - c0);
        if (tid < cn) rl[tid] = rlistT[t * 1024 + c0 + tid];
        __syncthreads();
        for (int e = tid; e < cn * 32; e += 256) {
            int r = e >> 5, k = e & 31;
            *(float4*)&arows[r][k * 4] =
                *(const float4*)(feat + ((size_t)t * GN + rl[r]) * DK + k * 4);
        }
        __syncthreads();

        for (int rb = 0; rb < cn; rb += 4) {
            int rn4 = min(4, cn - rb);
            for (int rr = 0; rr < rn4; ++rr) {     // no barriers inside
                const float* ap = &arows[rb + rr][par * 64];
                double s0=0.0,s1=0.0,s2=0.0,s3=0.0;
                double u0=0.0,u1=0.0,u2=0.0,u3=0.0;
                #pragma unroll
                for (int i = 0; i < 16; i += 4) {
                    float4 a0 = *(const float4*)(ap + i * 4);
                    float4 a1 = *(const float4*)(ap + i * 4 + 4);
                    float4 a2 = *(const float4*)(ap + i * 4 + 8);
                    float4 a3 = *(const float4*)(ap + i * 4 + 12);
                    ACC4(s0, a0, br0[i])     ACC4(s1, a1, br0[i + 1])
                    ACC4(s2, a2, br0[i + 2]) ACC4(s3, a3, br0[i + 3])
                    ACC4(u0, a0, br1[i])     ACC4(u1, a1, br1[i + 1])
                    ACC4(u2, a2, br1[i + 2]) ACC4(u3, a3, br1[i + 3])
                }
                double s = (s0 + s1) + (s2 + s3);
                double u = (u0 + u1) + (u2 + u3);
                double so = __shfl_xor(s, 1);      // partner k-half
                double uo = __shfl_xor(u, 1);
                if (par == 0) {
                    double v0 = (s + so) * rb0;
                    double v1 = (u + uo) * rb1;
                    if (v1 > v0) { cv[rr][row] = v1; ci[rr][row] = h1; }
                    else         { cv[rr][row] = v0; ci[rr][row] = h0; }  // tie -> h0
                }
            }
            __syncthreads();
            if (wave < rn4) {                      // 4 parallel reductions
                double v1 = cv[wave][lane];      int i1 = ci[wave][lane];
                double v2 = cv[wave][lane + 64]; int i2 = ci[wave][lane + 64];
                if (v2 > v1 || (v2 == v1 && i2 < i1)) { v1 = v2; i1 = i2; }
                #pragma unroll
                for (int off = 32; off > 0; off >>= 1) {
                    double ov = __shfl_down(v1, off);
                    int    oi = __shfl_down(i1, off);
                    if (ov > v1 || (ov == v1 && oi < i1)) { v1 = ov; i1 = oi; }
                }
                if (lane == 0) { resv[rb + wave] = v1; resi[rb + wave] = i1; }
            }
            __syncthreads();
        }

        if (tid < cn) {                            // bulk flush per chunk
            pbv[(size_t)bid * 1024 + c0 + tid] = resv[tid];
            pbi[(size_t)bid * 1024 + c0 + tid] = resi[tid];
        }
        __syncthreads();
    }
}

// ---------------------------------------------------------------------------
// Kernel 5: rescue-finalize + chain propagation. Pure LDS in the barrier
// loop; tail flush is STORES ONLY (R13/R14-proven - no bulk atomics from a
// single block: that was R15's 87 us regression).
// ---------------------------------------------------------------------------
__global__ __launch_bounds__(1024) void kgraph(const unsigned short* __restrict__ nxt16,
                                               const int* __restrict__ rcnt,
                                               const int* __restrict__ rlistT,
                                               const double* __restrict__ pbv,
                                               const int* __restrict__ pbi,
                                               int* __restrict__ chain_of) {
    __shared__ unsigned short ns[64 * 1024];   // 128 KB (row 63 unused pad)
    __shared__ int winner[2 * GN];             // 8 KB double-buffer
    __shared__ int rc[64];
    int g = threadIdx.x;                       // 0..1023

    #pragma unroll
    for (int i = 0; i < 8; ++i)
        gload_lds16((const char*)nxt16 + ((size_t)i * 1024 + g) * 16,
                    (char*)ns + ((size_t)i * 1024 + g) * 16);

    if (g < 63) rc[g] = rcnt[g];
    winner[g] = 0x7fffffff;
    chain_of[g] = g;                           // group 0: identity
    __syncthreads();                           // drains the global_load_lds

    // rescue fix-ups: thread g -> t = g>>4, ri = (g&15)+16k  (~2 iters/thread)
    int t0 = g >> 4;
    if (t0 < TT - 1) {
        for (int ri = g & 15; ri < rc[t0]; ri += 16) {
            double bv = -1e300; int bi = 0x7fffffff;
            #pragma unroll
            for (int q = 0; q < 4; ++q) {
                double v  = pbv[(size_t)(t0 * 4 + q) * 1024 + ri];
                int    ii = pbi[(size_t)(t0 * 4 + q) * 1024 + ri];
                if (v > bv || (v == bv && ii < bi)) { bv = v; bi = ii; }
            }
            ns[t0 * GN + rlistT[t0 * 1024 + ri]] = (unsigned short)bi;
        }
    }
    __syncthreads();

    int mychain = g;
    for (int t = 0; t < TT - 1; ++t) {
        int* Wa = winner + (t & 1) * GN;
        int* Wb = winner + ((t + 1) & 1) * GN;
        int j = ns[t * GN + g];                // local index in group t+1
        atomicMin(&Wa[j], mychain);
        Wb[g] = 0x7fffffff;
        __syncthreads();
        int w = Wa[g];
        mychain = (w == 0x7fffffff) ? (((t + 1) << 10) | g) : w;
        ns[t * GN + g] = (unsigned short)mychain;   // recycle consumed slot
        __syncthreads();
    }

    for (int t = 0; t < TT - 1; ++t)
        chain_of[(t + 1) * GN + g] = ns[t * GN + g];
}

// ---------------------------------------------------------------------------
// Kernel 6: chain lengths by owner count, 256 blocks (clen zeroed in kconv).
// ---------------------------------------------------------------------------
__global__ void kclen(const int* __restrict__ chain_of, int* __restrict__ clen) {
    int i = blockIdx.x * 256 + threadIdx.x;
    atomicAdd(&clen[chain_of[i]], 1);
}

// ---------------------------------------------------------------------------
// Kernel 7: per-block (1024-elem, coalesced) exclusive scan of kept lengths.
// ---------------------------------------------------------------------------
__global__ __launch_bounds__(1024) void kseg(const int* __restrict__ chain_of,
                                             const int* __restrict__ clen,
                                             const int* __restrict__ minp,
                                             int* __restrict__ oloc,
                                             int* __restrict__ partial) {
    __shared__ int ps[1024];
    int b = blockIdx.x, tid = threadIdx.x;
    int i = b * 1024 + tid;
    int ml = *minp;
    int cl = clen[i];
    int v = (chain_of[i] == i && cl >= ml) ? cl : 0;
    ps[tid] = v;
    __syncthreads();
    for (int off = 1; off < 1024; off <<= 1) {
        int add = (tid >= off) ? ps[tid - off] : 0;
        __syncthreads();
        ps[tid] += add;
        __syncthreads();
    }
    oloc[i] = ps[tid] - v;              // exclusive within block
    if (tid == 1023) partial[b] = ps[tid];
}

// ---------------------------------------------------------------------------
// Kernel 8: fused partial-scan + scatter + tail-zero.
// ---------------------------------------------------------------------------
__global__ __launch_bounds__(256) void kout(const float* __restrict__ coor,
                                            const float* __restrict__ feat,
                                            const int* __restrict__ chain_of,
                                            const int* __restrict__ clen,
                                            const int* __restrict__ oloc,
                                            const int* __restrict__ partial,
                                            const int* __restrict__ minp,
                                            float* __restrict__ out) {
    __shared__ int pb[64];
    __shared__ int stot;
    int tid = threadIdx.x;
    if (tid < 64) {
        int v = partial[tid];
        int acc = v;
        #pragma unroll
        for (int off = 1; off < 64; off <<= 1) {
            int o = __shfl_up(acc, off);
            if (tid >= off) acc += o;
        }
        pb[tid] = acc - v;
        if (tid == 63) stot = acc;
    }
    __syncthreads();

    int node = blockIdx.x * 4 + (tid >> 6);
    int lane = tid & 63;
    int s = chain_of[node];
    if (clen[s] >= *minp) {
        int row = oloc[s] + pb[s >> 10] + (node >> 10) - (s >> 10);
        float* orow = out + (size_t)row * OUTC;
        const float* f = feat + (size_t)node * DK;
        if (lane < 3) orow[lane] = coor[(size_t)node * 3 + lane];
        orow[3 + lane]  = f[lane];
        orow[67 + lane] = f[64 + lane];
    }

    int zrow = stot + blockIdx.x * 4 + (tid >> 6);
    if (zrow < NN) {
        float* orow = out + (size_t)zrow * OUTC;
        orow[lane] = 0.f;
        orow[64 + lane] = 0.f;
        if (lane < 3) orow[128 + lane] = 0.f;
    }
}

// ---------------------------------------------------------------------------
extern "C" void kernel_launch(void* const* d_in, const int* in_sizes, int n_in,
                              void* d_out, int out_size, void* d_ws, size_t ws_size,
                              hipStream_t stream) {
    const float* coor   = (const float*)d_in[0];   // [N,3]
    const float* feat   = (const float*)d_in[1];   // [N,128]
    const int*   minlen = (const int*)d_in[2];     // scalar
    float*       out    = (float*)d_out;           // [N,131] fp32

    char* ws = (char*)d_ws;
    double*         rnd      = (double*)(ws);                  // 512 KB
    float*          rnf      = (float*)(ws + 524288);          // 256 KB
    unsigned short* nxt16    = (unsigned short*)(ws + 786432); // 128 KB
    int*            chain_of = (int*)(ws + 917504);            // 256 KB
    int*            clen     = (int*)(ws + 1179648);           // 256 KB
    int*            oloc     = (int*)(ws + 1441792);           // 256 KB
    int*            rcnt     = (int*)(ws + 1703936);           // 63 ints
    int*            partial  = (int*)(ws + 1704192);           // 256 B
    int*            rlistT   = (int*)(ws + 1705216);           // 252 KB
    unsigned*       fh       = (unsigned*)(ws + 2097152);      // 16 MB
    float4*         tws      = (float4*)(ws + 18874368);       // 8.25 MB
    // pbv/pbi overlay tws (tws dead after kmerge; krescue runs after kmerge)
    double*         pbv      = (double*)(ws + 18874368);       // 252*1024*8 ~ 2 MB
    int*            pbi      = (int*)(ws + 18874368 + 2064384);// ~1 MB

    kconv<<<NN / 4, 256, 0, stream>>>(feat, fh, rnf, rnd, rcnt, clen);

    ksim<<<63 * 64, 256, 0, stream>>>(fh, rnf, tws);

    kmerge<<<63 * GN / 256, 256, 0, stream>>>(tws, nxt16, rcnt, rlistT);
    krescue<<<63 * 4, 256, 0, stream>>>(feat, rnd, rcnt, rlistT, pbv, pbi);

    kgraph<<<1, GN, 0, stream>>>(nxt16, rcnt, rlistT, pbv, pbi, chain_of);
    kclen<<<NN / 256, 256, 0, stream>>>(chain_of, clen);
    kseg<<<64, 1024, 0, stream>>>(chain_of, clen, minlen, oloc, partial);
    kout<<<NN / 4, 256, 0, stream>>>(coor, feat, chain_of, clen, oloc, partial,
                                     minlen, out);
}